// Round 21
// baseline (225.394 us; speedup 1.0000x reference)
//
#include <hip/hip_runtime.h>
#include <hip/hip_bf16.h>

typedef __attribute__((ext_vector_type(8))) short short8;
typedef __attribute__((ext_vector_type(8))) unsigned short ushort8;
typedef __attribute__((ext_vector_type(4))) unsigned short bfu4;
typedef __attribute__((ext_vector_type(4))) float f32x4;

__device__ __forceinline__ unsigned short f2bf(float f){
  return __builtin_bit_cast(unsigned short, __float2bfloat16(f));   // HW RNE cvt, pk-fusible
}
__device__ __forceinline__ float bf2f(unsigned short h){
  unsigned int u = ((unsigned int)h) << 16;
  return __builtin_bit_cast(float, u);
}
__device__ __forceinline__ float leaky(float x){ return x > 0.f ? x : 0.3f * x; }

// ---------------- FUSED: BN stats stage 1 (blocks 0..255) + ALL qk-path weight preps (256..1279) ----------------
__global__ __launch_bounds__(1024) void ca_stats_prep(const float* __restrict__ state,
    const int* __restrict__ agp, float* __restrict__ part, int B,
    const float* __restrict__ Wk, const float* __restrict__ Wv, const float* __restrict__ Wq,
    const float* __restrict__ Ws, const float* __restrict__ Wc,
    unsigned short* __restrict__ WkF2, unsigned short* __restrict__ WvF,
    unsigned short* __restrict__ WqF, unsigned short* __restrict__ WsF,
    unsigned short* __restrict__ WcF){
  __shared__ f32x4 red[16][4][64];   // 64KB (stats branch only)
  if (blockIdx.x < 256){
    int q = threadIdx.x & 63, sl = threadIdx.x >> 6;
    int ag = agp[0];
    int bPer = (B + 255) >> 8;
    int b0 = blockIdx.x * bPer;
    f32x4 zero4 = {0.f,0.f,0.f,0.f};
    f32x4 sC = zero4, ssC = zero4, sO = zero4, ssO = zero4;
    for (int b = sl; b < bPer; b += 16){
      int bb = b0 + b;
      if (bb >= B) continue;
      const float* row = state + ((size_t)bb << 12) + q*4;
      #pragma unroll
      for (int a = 0; a < 16; a++){
        f32x4 v = *(const f32x4*)(row + a*256);
        f32x4 vv = v * v;
        if (a == ag){ sC += v; ssC += vv; } else { sO += v; ssO += vv; }
      }
    }
    red[sl][0][q] = sC; red[sl][1][q] = ssC; red[sl][2][q] = sO; red[sl][3][q] = ssO;
    __syncthreads();
    if (threadIdx.x < 256){
      int st = threadIdx.x >> 6, qq = threadIdx.x & 63;
      f32x4 s = red[0][st][qq];
      #pragma unroll
      for (int g = 1; g < 16; g++) s += red[g][st][qq];
      *(f32x4*)(part + (size_t)blockIdx.x*1024 + st*256 + qq*4) = s;
    }
    return;
  }
  int bid2 = blockIdx.x - 256;
  int m = bid2 >> 8;
  if (m == 3){   // WsF + WcF, plain bf16, fragment-major (K=256)
    int item = ((bid2 & 255) << 10) | threadIdx.x;
    const float* W = (item < 131072) ? Ws : Wc;
    unsigned short* O = (item < 131072) ? WsF : WcF;
    int it2 = item & 131071;
    int n = it2 >> 8, d = it2 & 255;
    int h = n >> 6, nt = (n >> 4) & 3, j = n & 15;
    int kk = d >> 5, hi = (d >> 3) & 3, e = d & 7;
    O[(size_t)((h*8 + kk)*4 + nt)*512 + (hi*16 + j)*8 + e] = f2bf(W[(size_t)d*512 + n]);
    return;
  }
  int c = ((bid2 & 255) << 1) | (threadIdx.x >> 9);
  int n = threadIdx.x & 511;
  if (m == 2){   // WkF2: fragment-major Wk for the qk GEMM (A-operand, K=64)
    size_t idx = (size_t)c*512 + n;
    int h = (int)(idx >> 15), nn = (int)((idx >> 6) & 511), dd = (int)(idx & 63);
    int nt = nn >> 4, j = nn & 15, kq = dd >> 5, hi = (dd >> 3) & 3, e = dd & 7;
    WkF2[(size_t)((h*32 + nt)*2 + kq)*512 + (hi*16 + j)*8 + e] = f2bf(Wk[idx]);
    return;
  }
  // m=0: WvF, m=1: WqF (1/8 folded)
  int h = c >> 6, dd = c & 63;
  const float* W = (m == 0) ? Wv : Wq;
  float scale = (m == 1) ? 0.125f : 1.f;
  unsigned short v = f2bf(W[((size_t)h*512 + n)*64 + dd] * scale);
  int nt = (c >> 4) & 3, j = c & 15;
  int kk = n >> 5, hi = (n >> 3) & 3, e = n & 7;
  size_t fi = (size_t)((h*16 + kk)*4 + nt)*512 + (hi*16 + j)*8 + e;
  if (m == 0) WvF[fi] = v; else WqF[fi] = v;
}

// ---------------- BN statistics: stage 2 (parallel over d: grid=8, 32 d each) ----------------
__global__ __launch_bounds__(1024) void ca_stats_final(const float* __restrict__ part,
    float* __restrict__ stats, int nblk, int B){
  int dl = threadIdx.x & 31, sl = threadIdx.x >> 5;   // 32 slices
  int d = blockIdx.x*32 + dl;
  float sC = 0.f, ssC = 0.f, sO = 0.f, ssO = 0.f;
  for (int g = sl; g < nblk; g += 32){
    const float* p = part + (size_t)g * 1024;
    sC += p[d]; ssC += p[d+256]; sO += p[d+512]; ssO += p[d+768];
  }
  __shared__ float red[32][4][32];
  red[sl][0][dl] = sC; red[sl][1][dl] = ssC; red[sl][2][dl] = sO; red[sl][3][dl] = ssO;
  __syncthreads();
  if (sl == 0){
    sC = 0.f; ssC = 0.f; sO = 0.f; ssO = 0.f;
    #pragma unroll
    for (int g = 0; g < 32; g++){
      sC += red[g][0][dl]; ssC += red[g][1][dl]; sO += red[g][2][dl]; ssO += red[g][3][dl];
    }
    float nC = (float)B, nO = (float)B * 15.f;
    float mC = sC / nC, vC = ssC / nC - mC * mC;
    float mO = sO / nO, vO = ssO / nO - mO * mO;
    float rC = rsqrtf(vC + 1e-3f), rO = rsqrtf(vO + 1e-3f);
    stats[d] = rC; stats[d+256] = mC * rC; stats[d+512] = rO; stats[d+768] = mO * rO;
  }
}

// ---------------- weight prep (fallback only): folded WsT/WcT + biases ----------------
__global__ __launch_bounds__(256) void ca_prep_sc(const float* __restrict__ Ws,
    const float* __restrict__ bs, const float* __restrict__ Wc, const float* __restrict__ bc,
    const float* __restrict__ stats, unsigned short* __restrict__ WsT,
    unsigned short* __restrict__ WcT, float* __restrict__ bsp, float* __restrict__ bcp){
  int n = blockIdx.x, d = threadIdx.x;
  float rC = stats[d], mrC = stats[d+256], rO = stats[d+512], mrO = stats[d+768];
  float ws = Ws[(size_t)d*512 + n], wc = Wc[(size_t)d*512 + n];
  WsT[(size_t)n*256 + d] = f2bf(ws * rC);
  WcT[(size_t)n*256 + d] = f2bf(wc * rO);
  __shared__ float red[256];
  red[d] = mrC * ws;
  __syncthreads();
  for (int s = 128; s > 0; s >>= 1){ if (d < s) red[d] += red[d+s]; __syncthreads(); }
  if (d == 0) bsp[n] = bs[n] - red[0];
  __syncthreads();
  red[d] = mrO * wc;
  __syncthreads();
  for (int s = 128; s > 0; s >>= 1){ if (d < s) red[d] += red[d+s]; __syncthreads(); }
  if (d == 0) bcp[n] = bc[n] - red[0];
}

// ---------------- weight prep (fallback only): WkT/WvT/WqT ----------------
__global__ __launch_bounds__(512) void ca_prep_kvq(const float* __restrict__ Wk,
    const float* __restrict__ Wv, const float* __restrict__ Wq,
    unsigned short* __restrict__ WkT, unsigned short* __restrict__ WvT,
    unsigned short* __restrict__ WqT){
  int c = blockIdx.x & 511, m = blockIdx.x >> 9;
  int n = threadIdx.x;
  int h = c >> 6, dd = c & 63;
  const float* W = (m == 0) ? Wk : (m == 1) ? Wv : Wq;
  unsigned short* O = (m == 0) ? WkT : (m == 1) ? WvT : WqT;
  float scale = (m == 2) ? 0.125f : 1.f;
  O[(size_t)c*512 + n] = f2bf(W[((size_t)h*512 + n)*64 + dd] * scale);
}

// ---------------- Q kernel (fallback path only) ----------------
__global__ __launch_bounds__(512) void ca_q_kernel(const float* __restrict__ state,
    const int* __restrict__ agp,
    const unsigned short* __restrict__ WsT, const float* __restrict__ bsp,
    const unsigned short* __restrict__ WqT, unsigned short* __restrict__ Qws){
  __shared__ unsigned short U[32*512];
  __shared__ float bias_s[512];
  unsigned short* Alds = U;
  unsigned short* SE = U;
  int tid = threadIdx.x, lane = tid & 63, w = tid >> 6;
  int j = lane & 15, hi = lane >> 4;
  int b0 = blockIdx.x * 32;
  int ag = agp[0];

  for (int s = tid; s < 32*32; s += 512){
    int row = s >> 5, kg = s & 31;
    const float* p = state + (((size_t)(b0 + row) * 16 + ag) << 8) + kg * 8;
    f32x4 v0 = *(const f32x4*)p, v1 = *(const f32x4*)(p + 4);
    ushort8 hv;
    hv[0]=f2bf(v0[0]); hv[1]=f2bf(v0[1]); hv[2]=f2bf(v0[2]); hv[3]=f2bf(v0[3]);
    hv[4]=f2bf(v1[0]); hv[5]=f2bf(v1[1]); hv[6]=f2bf(v1[2]); hv[7]=f2bf(v1[3]);
    *(ushort8*)&Alds[row*256 + ((kg ^ (row & 7)) << 3)] = hv;
  }
  bias_s[tid & 511] = bsp[tid & 511];
  __syncthreads();

  int cb = w * 64;
  f32x4 zero4 = {0.f, 0.f, 0.f, 0.f};
  f32x4 acc[2][4];
  #pragma unroll
  for (int a1 = 0; a1 < 2; a1++)
    #pragma unroll
    for (int a2 = 0; a2 < 4; a2++) acc[a1][a2] = zero4;

  #pragma unroll
  for (int kk = 0; kk < 8; kk++){
    short8 bfr[4];
    #pragma unroll
    for (int nt = 0; nt < 4; nt++)
      bfr[nt] = *(const short8*)&WsT[(size_t)(cb + nt*16 + j)*256 + kk*32 + hi*8];
    #pragma unroll
    for (int mt = 0; mt < 2; mt++){
      int row = mt*16 + j;
      short8 afr = *(const short8*)&Alds[row*256 + ((((kk << 2) | hi) ^ (row & 7)) << 3)];
      #pragma unroll
      for (int nt = 0; nt < 4; nt++)
        acc[mt][nt] = __builtin_amdgcn_mfma_f32_16x16x32_bf16(afr, bfr[nt], acc[mt][nt], 0, 0, 0);
    }
  }
  __syncthreads();
  #pragma unroll
  for (int mt = 0; mt < 2; mt++)
    #pragma unroll
    for (int nt = 0; nt < 4; nt++)
      #pragma unroll
      for (int i = 0; i < 4; i++){
        int row = mt*16 + hi*4 + i, col = cb + nt*16 + j;
        float x = leaky(acc[mt][nt][i] + bias_s[col]);
        SE[row*512 + ((((col >> 3) ^ (row & 7)) << 3) | (col & 7))] = f2bf(x);
      }
  __syncthreads();

  f32x4 qa[2][4];
  #pragma unroll
  for (int a1 = 0; a1 < 2; a1++)
    #pragma unroll
    for (int a2 = 0; a2 < 4; a2++) qa[a1][a2] = zero4;
  #pragma unroll
  for (int kk = 0; kk < 16; kk++){
    short8 bfr[4];
    #pragma unroll
    for (int nt = 0; nt < 4; nt++)
      bfr[nt] = *(const short8*)&WqT[(size_t)(cb + nt*16 + j)*512 + kk*32 + hi*8];
    #pragma unroll
    for (int mt = 0; mt < 2; mt++){
      int row = mt*16 + j;
      short8 afr = *(const short8*)&SE[row*512 + ((((kk << 2) | hi) ^ (row & 7)) << 3)];
      #pragma unroll
      for (int nt = 0; nt < 4; nt++)
        qa[mt][nt] = __builtin_amdgcn_mfma_f32_16x16x32_bf16(afr, bfr[nt], qa[mt][nt], 0, 0, 0);
    }
  }
  #pragma unroll
  for (int mt = 0; mt < 2; mt++)
    #pragma unroll
    for (int nt = 0; nt < 4; nt++)
      #pragma unroll
      for (int i = 0; i < 4; i++)
        Qws[(size_t)(b0 + mt*16 + hi*4 + i)*512 + cb + nt*16 + j] = f2bf(qa[mt][nt][i]);
}

// ---------------- Q kernel (qk path): 1024 thr, 32 batches, normalized-input staging ----------------
__global__ __launch_bounds__(1024) void ca_q_kernel_qk(const float* __restrict__ state,
    const int* __restrict__ agp, const float* __restrict__ stats,
    const float* __restrict__ bs, const unsigned short* __restrict__ WsF,
    const unsigned short* __restrict__ WqF, const unsigned short* __restrict__ WkF2,
    unsigned short* __restrict__ QKws){
  __shared__ unsigned short U[2][16*512];   // 32KB: per-group union Alds/SE/Qlds
  __shared__ float bias_s[512];
  int tid = threadIdx.x, lane = tid & 63, w = tid >> 6;
  int g16 = w >> 3, wl = w & 7;
  int j = lane & 15, hi = lane >> 4;
  int b0 = blockIdx.x * 32 + g16 * 16;
  int ag = agp[0];
  f32x4 zero4 = {0.f, 0.f, 0.f, 0.f};
  unsigned short* Alds = U[g16];
  unsigned short* SE = U[g16];
  unsigned short* Qlds = U[g16];
  int sub = tid & 511;

  {
    int row = sub >> 5, kg = sub & 31;
    int kg0 = kg * 8;
    f32x4 rc0 = *(const f32x4*)(stats + kg0);
    f32x4 rc1 = *(const f32x4*)(stats + kg0 + 4);
    f32x4 mr0 = *(const f32x4*)(stats + 256 + kg0);
    f32x4 mr1 = *(const f32x4*)(stats + 256 + kg0 + 4);
    const float* p = state + (((size_t)(b0 + row) * 16 + ag) << 8) + kg0;
    f32x4 v0 = *(const f32x4*)p, v1 = *(const f32x4*)(p + 4);
    v0 = v0 * rc0 - mr0;
    v1 = v1 * rc1 - mr1;
    ushort8 hv;
    hv[0]=f2bf(v0[0]); hv[1]=f2bf(v0[1]); hv[2]=f2bf(v0[2]); hv[3]=f2bf(v0[3]);
    hv[4]=f2bf(v1[0]); hv[5]=f2bf(v1[1]); hv[6]=f2bf(v1[2]); hv[7]=f2bf(v1[3]);
    *(ushort8*)&Alds[row*256 + ((kg ^ (row & 7)) << 3)] = hv;
  }
  if (tid < 512) bias_s[tid] = bs[tid];
  __syncthreads();

  int cb = wl * 64;

  // GEMM1 (swapped): s_enc
  f32x4 acc[4];
  #pragma unroll
  for (int a2 = 0; a2 < 4; a2++) acc[a2] = zero4;
  #pragma unroll
  for (int kk = 0; kk < 8; kk++){
    short8 bfr[4];
    #pragma unroll
    for (int nt = 0; nt < 4; nt++)
      bfr[nt] = *(const short8*)&WsF[(size_t)((wl*8 + kk)*4 + nt)*512 + lane*8];
    short8 afr = *(const short8*)&Alds[j*256 + ((((kk << 2) | hi) ^ (j & 7)) << 3)];
    #pragma unroll
    for (int nt = 0; nt < 4; nt++)
      acc[nt] = __builtin_amdgcn_mfma_f32_16x16x32_bf16(bfr[nt], afr, acc[nt], 0, 0, 0);
  }
  __syncthreads();   // Alds dead; SE overlays it
  #pragma unroll
  for (int nt = 0; nt < 4; nt++){
    int nb = cb + nt*16 + hi*4;
    int g = nb >> 3;
    bfu4 pk;
    #pragma unroll
    for (int i = 0; i < 4; i++) pk[i] = f2bf(leaky(acc[nt][i] + bias_s[nb + i]));
    *(bfu4*)&SE[j*512 + ((g ^ (j & 7)) << 3) + (hi & 1)*4] = pk;
  }
  __syncthreads();

  // q-GEMM (swapped)
  f32x4 qa[4];
  #pragma unroll
  for (int a2 = 0; a2 < 4; a2++) qa[a2] = zero4;
  #pragma unroll
  for (int kk = 0; kk < 16; kk++){
    short8 bfr[4];
    #pragma unroll
    for (int nt = 0; nt < 4; nt++)
      bfr[nt] = *(const short8*)&WqF[(size_t)((wl*16 + kk)*4 + nt)*512 + lane*8];
    short8 afr = *(const short8*)&SE[j*512 + ((((kk << 2) | hi) ^ (j & 7)) << 3)];
    #pragma unroll
    for (int nt = 0; nt < 4; nt++)
      qa[nt] = __builtin_amdgcn_mfma_f32_16x16x32_bf16(bfr[nt], afr, qa[nt], 0, 0, 0);
  }
  __syncthreads();   // SE dead; Qlds overlays it
  #pragma unroll
  for (int nt = 0; nt < 4; nt++){
    int nb = cb + nt*16 + hi*4;
    int g = nb >> 3;
    bfu4 pk;
    #pragma unroll
    for (int i = 0; i < 4; i++) pk[i] = f2bf(qa[nt][i]);
    *(bfu4*)&Qlds[j*512 + ((g ^ (j & 7)) << 3) + (hi & 1)*4] = pk;
  }
  __syncthreads();

  // qk GEMM (swapped): C rows = n, cols = batch j; packed 8B stores
  short8 aq[2];
  #pragma unroll
  for (int kq = 0; kq < 2; kq++){
    int gq = wl*8 + kq*4 + hi;
    aq[kq] = *(const short8*)&Qlds[j*512 + ((gq ^ (j & 7)) << 3)];
  }
  for (int nt = 0; nt < 32; nt++){
    short8 bf0 = *(const short8*)&WkF2[(size_t)((wl*32 + nt)*2 + 0)*512 + lane*8];
    short8 bf1 = *(const short8*)&WkF2[(size_t)((wl*32 + nt)*2 + 1)*512 + lane*8];
    f32x4 qt = zero4;
    qt = __builtin_amdgcn_mfma_f32_16x16x32_bf16(bf0, aq[0], qt, 0, 0, 0);
    qt = __builtin_amdgcn_mfma_f32_16x16x32_bf16(bf1, aq[1], qt, 0, 0, 0);
    bfu4 pk;
    pk[0] = f2bf(qt[0]); pk[1] = f2bf(qt[1]); pk[2] = f2bf(qt[2]); pk[3] = f2bf(qt[3]);
    *(bfu4*)&QKws[((size_t)(b0 + j)*8 + wl)*512 + nt*16 + hi*4] = pk;
  }
}

// ---------------- main kernel (qk path): 4 batches/block, 4 waves/SIMD, QK prefetch ----------------
__global__ __launch_bounds__(512) void ca_main_kernel_qk(const float* __restrict__ state,
    const int* __restrict__ agp, const float* __restrict__ stats,
    const unsigned short* __restrict__ WcF, const float* __restrict__ bc,
    const unsigned short* __restrict__ WvF, const unsigned short* __restrict__ QKws,
    float* __restrict__ out){
  __shared__ unsigned short U[64*512];      // 64KB union: Alds (stride 256), SA (stride 512 swz)
  __shared__ float bias_s[512];
  __shared__ float Wl[4*16*8];              // wgt[b][a][h], 2KB
  unsigned short* Alds = U;
  unsigned short* SA = U;
  int tid = threadIdx.x, lane = tid & 63, w = tid >> 6;
  int j = lane & 15, hi = lane >> 4;
  int b0 = blockIdx.x * 4;
  int ag = agp[0];
  f32x4 zero4 = {0.f, 0.f, 0.f, 0.f};
  short8 zero8 = {0,0,0,0,0,0,0,0};

  {
    int kg0 = (tid & 31) * 8;
    f32x4 rc0 = *(const f32x4*)(stats + 512 + kg0);
    f32x4 rc1 = *(const f32x4*)(stats + 512 + kg0 + 4);
    f32x4 mr0 = *(const f32x4*)(stats + 768 + kg0);
    f32x4 mr1 = *(const f32x4*)(stats + 768 + kg0 + 4);
    f32x4 st0[4], st1[4];
    #pragma unroll
    for (int it = 0; it < 4; it++){
      int s = tid + 512*it;
      int row = s >> 5;
      int bl = row >> 4, ai = row & 15;
      if (ai < 15){
        int a = ai + (ai >= ag ? 1 : 0);
        const float* p = state + (((size_t)(b0 + bl) * 16 + a) << 8) + kg0;
        st0[it] = *(const f32x4*)p;
        st1[it] = *(const f32x4*)(p + 4);
      } else { st0[it] = zero4; st1[it] = zero4; }
    }
    #pragma unroll
    for (int it = 0; it < 4; it++){
      int s = tid + 512*it;
      int row = s >> 5, kg = s & 31;
      int ai = row & 15;
      ushort8 hv = {0,0,0,0,0,0,0,0};
      if (ai < 15){
        f32x4 v0 = st0[it] * rc0 - mr0;
        f32x4 v1 = st1[it] * rc1 - mr1;
        hv[0]=f2bf(v0[0]); hv[1]=f2bf(v0[1]); hv[2]=f2bf(v0[2]); hv[3]=f2bf(v0[3]);
        hv[4]=f2bf(v1[0]); hv[5]=f2bf(v1[1]); hv[6]=f2bf(v1[2]); hv[7]=f2bf(v1[3]);
      }
      *(ushort8*)&Alds[row*256 + ((kg ^ (row & 7)) << 3)] = hv;
    }
  }
  bias_s[tid] = bc[tid];
  __syncthreads();

  int cb = w * 64;

  // ---- GEMM1 (swapped): sa_enc rows [0,64)
  f32x4 acc[4][4];
  #pragma unroll
  for (int a1 = 0; a1 < 4; a1++)
    #pragma unroll
    for (int a2 = 0; a2 < 4; a2++) acc[a1][a2] = zero4;
  {
    short8 bcur[4], bnxt[4];
    #pragma unroll
    for (int nt = 0; nt < 4; nt++)
      bcur[nt] = *(const short8*)&WcF[(size_t)((w*8 + 0)*4 + nt)*512 + lane*8];
    #pragma unroll 2
    for (int kk = 0; kk < 8; kk++){
      if (kk < 7){
        #pragma unroll
        for (int nt = 0; nt < 4; nt++)
          bnxt[nt] = *(const short8*)&WcF[(size_t)((w*8 + kk + 1)*4 + nt)*512 + lane*8];
      }
      #pragma unroll
      for (int mt = 0; mt < 4; mt++){
        int row = mt*16 + j;
        short8 afr = *(const short8*)&Alds[row*256 + ((((kk << 2) | hi) ^ (row & 7)) << 3)];
        #pragma unroll
        for (int nt = 0; nt < 4; nt++)
          acc[mt][nt] = __builtin_amdgcn_mfma_f32_16x16x32_bf16(bcur[nt], afr, acc[mt][nt], 0, 0, 0);
      }
      #pragma unroll
      for (int nt = 0; nt < 4; nt++) bcur[nt] = bnxt[nt];
    }
  }
  // ---- prefetch QKws B-fragments for waves 0..3 (hides L2 latency under SA write + barrier)
  short8 bq[16];
  if (w < 4){
    size_t qbase = ((size_t)(b0 + w)*8 + (j & 7))*512;
    #pragma unroll
    for (int kk = 0; kk < 16; kk++)
      bq[kk] = *(const short8*)&QKws[qbase + kk*32 + hi*8];
  }
  __syncthreads();   // Alds dead; SA overlays
  #pragma unroll
  for (int mt = 0; mt < 4; mt++)
    #pragma unroll
    for (int nt = 0; nt < 4; nt++){
      int m = mt*16 + j;
      int nb = cb + nt*16 + hi*4;
      int g = nb >> 3;
      bfu4 pk;
      #pragma unroll
      for (int i = 0; i < 4; i++) pk[i] = f2bf(leaky(acc[mt][nt][i] + bias_s[nb + i]));
      *(bfu4*)&SA[m*512 + ((g ^ (m & 7)) << 3) + (hi & 1)*4] = pk;
    }
  __syncthreads();

  // ---- scores: waves 0..3 own batch b0+w (M=16 agents x 8 heads, K=512)
  if (w < 4){
    f32x4 qs = zero4;
    #pragma unroll
    for (int kk = 0; kk < 16; kk++){
      short8 bqv = (j < 8) ? bq[kk] : zero8;
      int row = w*16 + j;
      short8 afr = *(const short8*)&SA[row*512 + ((((kk << 2) | hi) ^ (row & 7)) << 3)];
      qs = __builtin_amdgcn_mfma_f32_16x16x32_bf16(afr, bqv, qs, 0, 0, 0);
    }
    float sv0 = qs[0], sv1 = qs[1], sv2 = qs[2], sv3 = qs[3];
    sv3 = (hi == 3) ? -1e30f : sv3;         // mask pad agent a=15
    float m = fmaxf(fmaxf(sv0, sv1), fmaxf(sv2, sv3));
    m = fmaxf(m, __shfl_xor(m, 16)); m = fmaxf(m, __shfl_xor(m, 32));
    float e0 = __expf(sv0-m), e1 = __expf(sv1-m), e2 = __expf(sv2-m), e3 = __expf(sv3-m);
    float sum = e0 + e1 + e2 + e3;
    sum += __shfl_xor(sum, 16); sum += __shfl_xor(sum, 32);
    float inv = 1.f / sum;
    if (j < 8){
      Wl[w*128 + (hi*4+0)*8 + j] = e0*inv;
      Wl[w*128 + (hi*4+1)*8 + j] = e1*inv;
      Wl[w*128 + (hi*4+2)*8 + j] = e2*inv;
      Wl[w*128 + (hi*4+3)*8 + j] = e3*inv;
    }
  }

  // ---- GEMM2-V (unswapped), rows [0,64)
  f32x4 va[4][4];
  #pragma unroll
  for (int a1 = 0; a1 < 4; a1++)
    #pragma unroll
    for (int a2 = 0; a2 < 4; a2++) va[a1][a2] = zero4;
  {
    short8 bcur[4], bnxt[4];
    #pragma unroll
    for (int nt = 0; nt < 4; nt++)
      bcur[nt] = *(const short8*)&WvF[(size_t)((w*16 + 0)*4 + nt)*512 + lane*8];
    #pragma unroll 4
    for (int kk = 0; kk < 16; kk++){
      if (kk < 15){
        #pragma unroll
        for (int nt = 0; nt < 4; nt++)
          bnxt[nt] = *(const short8*)&WvF[(size_t)((w*16 + kk + 1)*4 + nt)*512 + lane*8];
      }
      #pragma unroll
      for (int mt = 0; mt < 4; mt++){
        int row = mt*16 + j;
        short8 afr = *(const short8*)&SA[row*512 + ((((kk << 2) | hi) ^ (row & 7)) << 3)];
        #pragma unroll
        for (int nt = 0; nt < 4; nt++)
          va[mt][nt] = __builtin_amdgcn_mfma_f32_16x16x32_bf16(afr, bcur[nt], va[mt][nt], 0, 0, 0);
      }
      #pragma unroll
      for (int nt = 0; nt < 4; nt++) bcur[nt] = bnxt[nt];
    }
  }
  __syncthreads();   // Wl writes (pre-V) now visible to all waves

  // ---- att = sum_a wgt * leaky(V); wave w = head w reads wgt[mt][a][w]
  #pragma unroll
  for (int mt = 0; mt < 4; mt++){
    float w0 = Wl[mt*128 + (hi*4+0)*8 + w];
    float w1 = Wl[mt*128 + (hi*4+1)*8 + w];
    float w2 = Wl[mt*128 + (hi*4+2)*8 + w];
    float w3 = Wl[mt*128 + (hi*4+3)*8 + w];
    float ap0 = w0*leaky(va[mt][0][0]) + w1*leaky(va[mt][0][1]) + w2*leaky(va[mt][0][2]) + w3*leaky(va[mt][0][3]);
    float ap1 = w0*leaky(va[mt][1][0]) + w1*leaky(va[mt][1][1]) + w2*leaky(va[mt][1][2]) + w3*leaky(va[mt][1][3]);
    float ap2 = w0*leaky(va[mt][2][0]) + w1*leaky(va[mt][2][1]) + w2*leaky(va[mt][2][2]) + w3*leaky(va[mt][2][3]);
    float ap3 = w0*leaky(va[mt][3][0]) + w1*leaky(va[mt][3][1]) + w2*leaky(va[mt][3][2]) + w3*leaky(va[mt][3][3]);
    ap0 += __shfl_xor(ap0, 16); ap0 += __shfl_xor(ap0, 32);
    ap1 += __shfl_xor(ap1, 16); ap1 += __shfl_xor(ap1, 32);
    ap2 += __shfl_xor(ap2, 16); ap2 += __shfl_xor(ap2, 32);
    ap3 += __shfl_xor(ap3, 16); ap3 += __shfl_xor(ap3, 32);
    float val = (hi == 0) ? ap0 : (hi == 1) ? ap1 : (hi == 2) ? ap2 : ap3;
    out[(size_t)(b0 + mt)*512 + cb + lane] = val;
  }
}

// ---------------- main kernel (fallback = R9, unchanged) ----------------
__global__ __launch_bounds__(512) void ca_main_kernel(const float* __restrict__ state,
    const int* __restrict__ agp,
    const unsigned short* __restrict__ WcT, const float* __restrict__ bcp,
    const unsigned short* __restrict__ WkT, const unsigned short* __restrict__ WvT,
    const unsigned short* __restrict__ Qws, float* __restrict__ out){
  __shared__ unsigned short U[128*512];
  __shared__ unsigned short Qs[8*512];
  __shared__ float bias_s[512];
  unsigned short* Alds = U;
  unsigned short* SA = U;
  int tid = threadIdx.x, lane = tid & 63, w = tid >> 6;
  int j = lane & 15, hi = lane >> 4;
  int b0 = blockIdx.x * 8;
  int ag = agp[0];
  f32x4 zero4 = {0.f, 0.f, 0.f, 0.f};

  #pragma unroll
  for (int g = 0; g < 2; g++){
    f32x4 st0[4], st1[4];
    #pragma unroll
    for (int it = 0; it < 4; it++){
      int s = tid + 512*(g*4 + it);
      int row = s >> 5, kg = s & 31;
      int bl = row >> 4, ai = row & 15;
      if (ai < 15){
        int a = ai + (ai >= ag ? 1 : 0);
        const float* p = state + (((size_t)(b0 + bl) * 16 + a) << 8) + kg * 8;
        st0[it] = *(const f32x4*)p;
        st1[it] = *(const f32x4*)(p + 4);
      } else { st0[it] = zero4; st1[it] = zero4; }
    }
    #pragma unroll
    for (int it = 0; it < 4; it++){
      int s = tid + 512*(g*4 + it);
      int row = s >> 5, kg = s & 31;
      ushort8 hv;
      hv[0]=f2bf(st0[it][0]); hv[1]=f2bf(st0[it][1]); hv[2]=f2bf(st0[it][2]); hv[3]=f2bf(st0[it][3]);
      hv[4]=f2bf(st1[it][0]); hv[5]=f2bf(st1[it][1]); hv[6]=f2bf(st1[it][2]); hv[7]=f2bf(st1[it][3]);
      *(ushort8*)&Alds[row*256 + ((kg ^ (row & 7)) << 3)] = hv;
    }
  }
  *(ushort8*)&Qs[tid*8] = *(const ushort8*)&Qws[(size_t)b0*512 + tid*8];
  bias_s[tid] = bcp[tid];
  __syncthreads();

  int cb = w * 64;

  f32x4 acc[8][4];
  #pragma unroll
  for (int a1 = 0; a1 < 8; a1++)
    #pragma unroll
    for (int a2 = 0; a2 < 4; a2++) acc[a1][a2] = zero4;
  {
    short8 bcur[4], bnxt[4];
    #pragma unroll
    for (int nt = 0; nt < 4; nt++)
      bcur[nt] = *(const short8*)&WcT[(size_t)(cb + nt*16 + j)*256 + hi*8];
    #pragma unroll 1
    for (int kk = 0; kk < 8; kk++){
      if (kk < 7){
        #pragma unroll
        for (int nt = 0; nt < 4; nt++)
          bnxt[nt] = *(const short8*)&WcT[(size_t)(cb + nt*16 + j)*256 + (kk+1)*32 + hi*8];
      }
      #pragma unroll
      for (int mt = 0; mt < 8; mt++){
        int row = mt*16 + j;
        short8 afr = *(const short8*)&Alds[row*256 + ((((kk << 2) | hi) ^ (row & 7)) << 3)];
        #pragma unroll
        for (int nt = 0; nt < 4; nt++)
          acc[mt][nt] = __builtin_amdgcn_mfma_f32_16x16x32_bf16(afr, bcur[nt], acc[mt][nt], 0, 0, 0);
      }
      #pragma unroll
      for (int nt = 0; nt < 4; nt++) bcur[nt] = bnxt[nt];
    }
  }
  __syncthreads();
  #pragma unroll
  for (int mt = 0; mt < 8; mt++)
    #pragma unroll
    for (int nt = 0; nt < 4; nt++)
      #pragma unroll
      for (int i = 0; i < 4; i++){
        int row = mt*16 + hi*4 + i, col = cb + nt*16 + j;
        float x = leaky(acc[mt][nt][i] + bias_s[col]);
        SA[row*512 + ((((col >> 3) ^ (row & 7)) << 3) | (col & 7))] = f2bf(x);
      }
  __syncthreads();

  f32x4 ka[8][4];
  #pragma unroll
  for (int a1 = 0; a1 < 8; a1++)
    #pragma unroll
    for (int a2 = 0; a2 < 4; a2++) ka[a1][a2] = zero4;
  {
    short8 bcur[4], bnxt[4];
    #pragma unroll
    for (int nt = 0; nt < 4; nt++)
      bcur[nt] = *(const short8*)&WkT[(size_t)(cb + nt*16 + j)*512 + hi*8];
    #pragma unroll 1
    for (int kk = 0; kk < 16; kk++){
      if (kk < 15){
        #pragma unroll
        for (int nt = 0; nt < 4; nt++)
          bnxt[nt] = *(const short8*)&WkT[(size_t)(cb + nt*16 + j)*512 + (kk+1)*32 + hi*8];
      }
      #pragma unroll
      for (int mt = 0; mt < 8; mt++){
        int row = mt*16 + j;
        short8 afr = *(const short8*)&SA[row*512 + ((((kk << 2) | hi) ^ (row & 7)) << 3)];
        #pragma unroll
        for (int nt = 0; nt < 4; nt++)
          ka[mt][nt] = __builtin_amdgcn_mfma_f32_16x16x32_bf16(afr, bcur[nt], ka[mt][nt], 0, 0, 0);
      }
      #pragma unroll
      for (int nt = 0; nt < 4; nt++) bcur[nt] = bnxt[nt];
    }
  }

  float wgt[8][4];
  #pragma unroll
  for (int mt = 0; mt < 8; mt++){
    float sv[4];
    #pragma unroll
    for (int i = 0; i < 4; i++){
      float t = 0.f;
      #pragma unroll
      for (int nt = 0; nt < 4; nt++)
        t += bf2f(Qs[mt*512 + cb + nt*16 + j]) * ka[mt][nt][i];
      t += __shfl_xor(t, 1); t += __shfl_xor(t, 2);
      t += __shfl_xor(t, 4); t += __shfl_xor(t, 8);
      sv[i] = t;
    }
    sv[3] = (hi == 3) ? -1e30f : sv[3];
    float m = fmaxf(fmaxf(sv[0], sv[1]), fmaxf(sv[2], sv[3]));
    m = fmaxf(m, __shfl_xor(m, 16)); m = fmaxf(m, __shfl_xor(m, 32));
    float e0 = __expf(sv[0]-m), e1 = __expf(sv[1]-m), e2 = __expf(sv[2]-m), e3 = __expf(sv[3]-m);
    float sum = e0 + e1 + e2 + e3;
    sum += __shfl_xor(sum, 16); sum += __shfl_xor(sum, 32);
    float inv = 1.f / sum;
    wgt[mt][0] = e0*inv; wgt[mt][1] = e1*inv; wgt[mt][2] = e2*inv; wgt[mt][3] = e3*inv;
  }

  f32x4 va[8][4];
  #pragma unroll
  for (int a1 = 0; a1 < 8; a1++)
    #pragma unroll
    for (int a2 = 0; a2 < 4; a2++) va[a1][a2] = zero4;
  {
    short8 bcur[4], bnxt[4];
    #pragma unroll
    for (int nt = 0; nt < 4; nt++)
      bcur[nt] = *(const short8*)&WvT[(size_t)(cb + nt*16 + j)*512 + hi*8];
    #pragma unroll 1
    for (int kk = 0; kk < 16; kk++){
      if (kk < 15){
        #pragma unroll
        for (int nt = 0; nt < 4; nt++)
          bnxt[nt] = *(const short8*)&WvT[(size_t)(cb + nt*16 + j)*512 + (kk+1)*32 + hi*8];
      }
      #pragma unroll
      for (int mt = 0; mt < 8; mt++){
        int row = mt*16 + j;
        short8 afr = *(const short8*)&SA[row*512 + ((((kk << 2) | hi) ^ (row & 7)) << 3)];
        #pragma unroll
        for (int nt = 0; nt < 4; nt++)
          va[mt][nt] = __builtin_amdgcn_mfma_f32_16x16x32_bf16(afr, bcur[nt], va[mt][nt], 0, 0, 0);
      }
      #pragma unroll
      for (int nt = 0; nt < 4; nt++) bcur[nt] = bnxt[nt];
    }
  }

  #pragma unroll
  for (int mt = 0; mt < 8; mt++){
    float ap0 = 0.f, ap1 = 0.f, ap2 = 0.f, ap3 = 0.f;
    #pragma unroll
    for (int i = 0; i < 4; i++){
      float wv = wgt[mt][i];
      ap0 += wv * leaky(va[mt][0][i]);
      ap1 += wv * leaky(va[mt][1][i]);
      ap2 += wv * leaky(va[mt][2][i]);
      ap3 += wv * leaky(va[mt][3][i]);
    }
    ap0 += __shfl_xor(ap0, 16); ap0 += __shfl_xor(ap0, 32);
    ap1 += __shfl_xor(ap1, 16); ap1 += __shfl_xor(ap1, 32);
    ap2 += __shfl_xor(ap2, 16); ap2 += __shfl_xor(ap2, 32);
    ap3 += __shfl_xor(ap3, 16); ap3 += __shfl_xor(ap3, 32);
    float val = (hi == 0) ? ap0 : (hi == 1) ? ap1 : (hi == 2) ? ap2 : ap3;
    out[(size_t)(b0 + mt)*512 + cb + lane] = val;
  }
}

extern "C" void kernel_launch(void* const* d_in, const int* in_sizes, int n_in,
                              void* d_out, int out_size, void* d_ws, size_t ws_size,
                              hipStream_t stream) {
  const float* state = (const float*)d_in[0];
  const int*   agp   = (const int*)d_in[1];
  const float* Ws    = (const float*)d_in[2];
  const float* bs    = (const float*)d_in[3];
  const float* Wc    = (const float*)d_in[4];
  const float* bc    = (const float*)d_in[5];
  const float* Wk    = (const float*)d_in[6];
  const float* Wq    = (const float*)d_in[7];
  const float* Wv    = (const float*)d_in[8];
  float* out = (float*)d_out;
  int B = in_sizes[0] / 4096;   // state is (B,16,256)

  char* wsb = (char*)d_ws;
  float* part  = (float*)wsb;                                   // 1 MB
  float* stats = (float*)(wsb + (1 << 20));                     // 4 KB
  float* bsp   = (float*)(wsb + (1 << 20) + 4096);              // 2 KB
  float* bcp   = (float*)(wsb + (1 << 20) + 6144);              // 2 KB
  unsigned short* WsT  = (unsigned short*)(wsb + (1 << 20) + 8192);
  unsigned short* WcT  = WsT  + 512*256;
  unsigned short* WkT  = WcT  + 512*256;
  unsigned short* WvT  = WkT  + 512*512;
  unsigned short* WqT  = WvT  + 512*512;
  unsigned short* WkF2 = WqT  + 512*512;         // fragment-major Wk (qk GEMM)
  unsigned short* Qws  = WkF2 + 512*512;         // B*512  (fallback only)
  unsigned short* QKws = Qws  + (size_t)B*512;   // B*8*512
  unsigned short* WsF  = Qws;                    // F-layouts overlay Qws (qk path)
  unsigned short* WcF  = WsF + 512*256;
  unsigned short* WqF  = WcF + 512*256;
  unsigned short* WvF  = WqF + 512*512;

  size_t need = ((size_t)(1 << 20) + 8192)
              + 2ull*(512*256 + 512*256 + 512*512 + 512*512 + 512*512 + 512*512)
              + 2ull*B*512 + 2ull*B*8*512;
  bool qkp = (ws_size >= need);

  hipLaunchKernelGGL(ca_stats_prep, dim3(1280), dim3(1024), 0, stream, state, agp, part, B,
                     Wk, Wv, Wq, Ws, Wc, WkF2, WvF, WqF, WsF, WcF);
  hipLaunchKernelGGL(ca_stats_final, dim3(8), dim3(1024), 0, stream, part, stats, 256, B);
  if (qkp){
    hipLaunchKernelGGL(ca_q_kernel_qk,   dim3(B/32),dim3(1024), 0, stream, state, agp, stats, bs, WsF, WqF, WkF2, QKws);
    hipLaunchKernelGGL(ca_main_kernel_qk,dim3(B/4), dim3(512), 0, stream, state, agp, stats, WcF, bc, WvF, QKws, out);
  } else {
    hipLaunchKernelGGL(ca_prep_sc,       dim3(512), dim3(256), 0, stream, Ws, bs, Wc, bc, stats, WsT, WcT, bsp, bcp);
    hipLaunchKernelGGL(ca_prep_kvq,      dim3(1536),dim3(512), 0, stream, Wk, Wv, Wq, WkT, WvT, WqT);
    hipLaunchKernelGGL(ca_q_kernel,      dim3(B/32),dim3(512), 0, stream, state, agp, WsT, bsp, WqT, Qws);
    hipLaunchKernelGGL(ca_main_kernel,   dim3(B/8), dim3(512), 0, stream, state, agp, WcT, bcp, WkT, WvT, Qws, out);
  }
}

// Round 22
// 196.694 us; speedup vs baseline: 1.1459x; 1.1459x over previous
//
#include <hip/hip_runtime.h>
#include <hip/hip_bf16.h>

typedef __attribute__((ext_vector_type(8))) short short8;
typedef __attribute__((ext_vector_type(8))) unsigned short ushort8;
typedef __attribute__((ext_vector_type(4))) unsigned short bfu4;
typedef __attribute__((ext_vector_type(4))) float f32x4;

__device__ __forceinline__ unsigned short f2bf(float f){
  return __builtin_bit_cast(unsigned short, __float2bfloat16(f));   // HW RNE cvt, pk-fusible
}
__device__ __forceinline__ float bf2f(unsigned short h){
  unsigned int u = ((unsigned int)h) << 16;
  return __builtin_bit_cast(float, u);
}
__device__ __forceinline__ float leaky(float x){ return x > 0.f ? x : 0.3f * x; }

// ---------------- FUSED: BN stats stage 1 (blocks 0..255) + ALL qk-path weight preps (256..1279) ----------------
__global__ __launch_bounds__(1024) void ca_stats_prep(const float* __restrict__ state,
    const int* __restrict__ agp, float* __restrict__ part, int B,
    const float* __restrict__ Wk, const float* __restrict__ Wv, const float* __restrict__ Wq,
    const float* __restrict__ Ws, const float* __restrict__ Wc,
    unsigned short* __restrict__ WkF2, unsigned short* __restrict__ WvF,
    unsigned short* __restrict__ WqF, unsigned short* __restrict__ WsF,
    unsigned short* __restrict__ WcF){
  __shared__ f32x4 red[16][4][64];   // 64KB (stats branch only)
  if (blockIdx.x < 256){
    int q = threadIdx.x & 63, sl = threadIdx.x >> 6;
    int ag = agp[0];
    int bPer = (B + 255) >> 8;
    int b0 = blockIdx.x * bPer;
    f32x4 zero4 = {0.f,0.f,0.f,0.f};
    f32x4 sC = zero4, ssC = zero4, sO = zero4, ssO = zero4;
    for (int b = sl; b < bPer; b += 16){
      int bb = b0 + b;
      if (bb >= B) continue;
      const float* row = state + ((size_t)bb << 12) + q*4;
      #pragma unroll
      for (int a = 0; a < 16; a++){
        f32x4 v = *(const f32x4*)(row + a*256);
        f32x4 vv = v * v;
        if (a == ag){ sC += v; ssC += vv; } else { sO += v; ssO += vv; }
      }
    }
    red[sl][0][q] = sC; red[sl][1][q] = ssC; red[sl][2][q] = sO; red[sl][3][q] = ssO;
    __syncthreads();
    if (threadIdx.x < 256){
      int st = threadIdx.x >> 6, qq = threadIdx.x & 63;
      f32x4 s = red[0][st][qq];
      #pragma unroll
      for (int g = 1; g < 16; g++) s += red[g][st][qq];
      *(f32x4*)(part + (size_t)blockIdx.x*1024 + st*256 + qq*4) = s;
    }
    return;
  }
  int bid2 = blockIdx.x - 256;
  int m = bid2 >> 8;
  if (m == 3){   // WsF + WcF, plain bf16, fragment-major (K=256)
    int item = ((bid2 & 255) << 10) | threadIdx.x;
    const float* W = (item < 131072) ? Ws : Wc;
    unsigned short* O = (item < 131072) ? WsF : WcF;
    int it2 = item & 131071;
    int n = it2 >> 8, d = it2 & 255;
    int h = n >> 6, nt = (n >> 4) & 3, j = n & 15;
    int kk = d >> 5, hi = (d >> 3) & 3, e = d & 7;
    O[(size_t)((h*8 + kk)*4 + nt)*512 + (hi*16 + j)*8 + e] = f2bf(W[(size_t)d*512 + n]);
    return;
  }
  int c = ((bid2 & 255) << 1) | (threadIdx.x >> 9);
  int n = threadIdx.x & 511;
  if (m == 2){   // WkF2: fragment-major Wk for the qk GEMM (A-operand, K=64)
    size_t idx = (size_t)c*512 + n;
    int h = (int)(idx >> 15), nn = (int)((idx >> 6) & 511), dd = (int)(idx & 63);
    int nt = nn >> 4, j = nn & 15, kq = dd >> 5, hi = (dd >> 3) & 3, e = dd & 7;
    WkF2[(size_t)((h*32 + nt)*2 + kq)*512 + (hi*16 + j)*8 + e] = f2bf(Wk[idx]);
    return;
  }
  // m=0: WvF, m=1: WqF (1/8 folded)
  int h = c >> 6, dd = c & 63;
  const float* W = (m == 0) ? Wv : Wq;
  float scale = (m == 1) ? 0.125f : 1.f;
  unsigned short v = f2bf(W[((size_t)h*512 + n)*64 + dd] * scale);
  int nt = (c >> 4) & 3, j = c & 15;
  int kk = n >> 5, hi = (n >> 3) & 3, e = n & 7;
  size_t fi = (size_t)((h*16 + kk)*4 + nt)*512 + (hi*16 + j)*8 + e;
  if (m == 0) WvF[fi] = v; else WqF[fi] = v;
}

// ---------------- BN statistics: stage 2 (parallel over d: grid=8, 32 d each) ----------------
__global__ __launch_bounds__(1024) void ca_stats_final(const float* __restrict__ part,
    float* __restrict__ stats, int nblk, int B){
  int dl = threadIdx.x & 31, sl = threadIdx.x >> 5;   // 32 slices
  int d = blockIdx.x*32 + dl;
  float sC = 0.f, ssC = 0.f, sO = 0.f, ssO = 0.f;
  for (int g = sl; g < nblk; g += 32){
    const float* p = part + (size_t)g * 1024;
    sC += p[d]; ssC += p[d+256]; sO += p[d+512]; ssO += p[d+768];
  }
  __shared__ float red[32][4][32];
  red[sl][0][dl] = sC; red[sl][1][dl] = ssC; red[sl][2][dl] = sO; red[sl][3][dl] = ssO;
  __syncthreads();
  if (sl == 0){
    sC = 0.f; ssC = 0.f; sO = 0.f; ssO = 0.f;
    #pragma unroll
    for (int g = 0; g < 32; g++){
      sC += red[g][0][dl]; ssC += red[g][1][dl]; sO += red[g][2][dl]; ssO += red[g][3][dl];
    }
    float nC = (float)B, nO = (float)B * 15.f;
    float mC = sC / nC, vC = ssC / nC - mC * mC;
    float mO = sO / nO, vO = ssO / nO - mO * mO;
    float rC = rsqrtf(vC + 1e-3f), rO = rsqrtf(vO + 1e-3f);
    stats[d] = rC; stats[d+256] = mC * rC; stats[d+512] = rO; stats[d+768] = mO * rO;
  }
}

// ---------------- weight prep (fallback only): folded WsT/WcT + biases ----------------
__global__ __launch_bounds__(256) void ca_prep_sc(const float* __restrict__ Ws,
    const float* __restrict__ bs, const float* __restrict__ Wc, const float* __restrict__ bc,
    const float* __restrict__ stats, unsigned short* __restrict__ WsT,
    unsigned short* __restrict__ WcT, float* __restrict__ bsp, float* __restrict__ bcp){
  int n = blockIdx.x, d = threadIdx.x;
  float rC = stats[d], mrC = stats[d+256], rO = stats[d+512], mrO = stats[d+768];
  float ws = Ws[(size_t)d*512 + n], wc = Wc[(size_t)d*512 + n];
  WsT[(size_t)n*256 + d] = f2bf(ws * rC);
  WcT[(size_t)n*256 + d] = f2bf(wc * rO);
  __shared__ float red[256];
  red[d] = mrC * ws;
  __syncthreads();
  for (int s = 128; s > 0; s >>= 1){ if (d < s) red[d] += red[d+s]; __syncthreads(); }
  if (d == 0) bsp[n] = bs[n] - red[0];
  __syncthreads();
  red[d] = mrO * wc;
  __syncthreads();
  for (int s = 128; s > 0; s >>= 1){ if (d < s) red[d] += red[d+s]; __syncthreads(); }
  if (d == 0) bcp[n] = bc[n] - red[0];
}

// ---------------- weight prep (fallback only): WkT/WvT/WqT ----------------
__global__ __launch_bounds__(512) void ca_prep_kvq(const float* __restrict__ Wk,
    const float* __restrict__ Wv, const float* __restrict__ Wq,
    unsigned short* __restrict__ WkT, unsigned short* __restrict__ WvT,
    unsigned short* __restrict__ WqT){
  int c = blockIdx.x & 511, m = blockIdx.x >> 9;
  int n = threadIdx.x;
  int h = c >> 6, dd = c & 63;
  const float* W = (m == 0) ? Wk : (m == 1) ? Wv : Wq;
  unsigned short* O = (m == 0) ? WkT : (m == 1) ? WvT : WqT;
  float scale = (m == 2) ? 0.125f : 1.f;
  O[(size_t)c*512 + n] = f2bf(W[((size_t)h*512 + n)*64 + dd] * scale);
}

// ---------------- Q kernel (fallback path only) ----------------
__global__ __launch_bounds__(512) void ca_q_kernel(const float* __restrict__ state,
    const int* __restrict__ agp,
    const unsigned short* __restrict__ WsT, const float* __restrict__ bsp,
    const unsigned short* __restrict__ WqT, unsigned short* __restrict__ Qws){
  __shared__ unsigned short U[32*512];
  __shared__ float bias_s[512];
  unsigned short* Alds = U;
  unsigned short* SE = U;
  int tid = threadIdx.x, lane = tid & 63, w = tid >> 6;
  int j = lane & 15, hi = lane >> 4;
  int b0 = blockIdx.x * 32;
  int ag = agp[0];

  for (int s = tid; s < 32*32; s += 512){
    int row = s >> 5, kg = s & 31;
    const float* p = state + (((size_t)(b0 + row) * 16 + ag) << 8) + kg * 8;
    f32x4 v0 = *(const f32x4*)p, v1 = *(const f32x4*)(p + 4);
    ushort8 hv;
    hv[0]=f2bf(v0[0]); hv[1]=f2bf(v0[1]); hv[2]=f2bf(v0[2]); hv[3]=f2bf(v0[3]);
    hv[4]=f2bf(v1[0]); hv[5]=f2bf(v1[1]); hv[6]=f2bf(v1[2]); hv[7]=f2bf(v1[3]);
    *(ushort8*)&Alds[row*256 + ((kg ^ (row & 7)) << 3)] = hv;
  }
  bias_s[tid & 511] = bsp[tid & 511];
  __syncthreads();

  int cb = w * 64;
  f32x4 zero4 = {0.f, 0.f, 0.f, 0.f};
  f32x4 acc[2][4];
  #pragma unroll
  for (int a1 = 0; a1 < 2; a1++)
    #pragma unroll
    for (int a2 = 0; a2 < 4; a2++) acc[a1][a2] = zero4;

  #pragma unroll
  for (int kk = 0; kk < 8; kk++){
    short8 bfr[4];
    #pragma unroll
    for (int nt = 0; nt < 4; nt++)
      bfr[nt] = *(const short8*)&WsT[(size_t)(cb + nt*16 + j)*256 + kk*32 + hi*8];
    #pragma unroll
    for (int mt = 0; mt < 2; mt++){
      int row = mt*16 + j;
      short8 afr = *(const short8*)&Alds[row*256 + ((((kk << 2) | hi) ^ (row & 7)) << 3)];
      #pragma unroll
      for (int nt = 0; nt < 4; nt++)
        acc[mt][nt] = __builtin_amdgcn_mfma_f32_16x16x32_bf16(afr, bfr[nt], acc[mt][nt], 0, 0, 0);
    }
  }
  __syncthreads();
  #pragma unroll
  for (int mt = 0; mt < 2; mt++)
    #pragma unroll
    for (int nt = 0; nt < 4; nt++)
      #pragma unroll
      for (int i = 0; i < 4; i++){
        int row = mt*16 + hi*4 + i, col = cb + nt*16 + j;
        float x = leaky(acc[mt][nt][i] + bias_s[col]);
        SE[row*512 + ((((col >> 3) ^ (row & 7)) << 3) | (col & 7))] = f2bf(x);
      }
  __syncthreads();

  f32x4 qa[2][4];
  #pragma unroll
  for (int a1 = 0; a1 < 2; a1++)
    #pragma unroll
    for (int a2 = 0; a2 < 4; a2++) qa[a1][a2] = zero4;
  #pragma unroll
  for (int kk = 0; kk < 16; kk++){
    short8 bfr[4];
    #pragma unroll
    for (int nt = 0; nt < 4; nt++)
      bfr[nt] = *(const short8*)&WqT[(size_t)(cb + nt*16 + j)*512 + kk*32 + hi*8];
    #pragma unroll
    for (int mt = 0; mt < 2; mt++){
      int row = mt*16 + j;
      short8 afr = *(const short8*)&SE[row*512 + ((((kk << 2) | hi) ^ (row & 7)) << 3)];
      #pragma unroll
      for (int nt = 0; nt < 4; nt++)
        qa[mt][nt] = __builtin_amdgcn_mfma_f32_16x16x32_bf16(afr, bfr[nt], qa[mt][nt], 0, 0, 0);
    }
  }
  #pragma unroll
  for (int mt = 0; mt < 2; mt++)
    #pragma unroll
    for (int nt = 0; nt < 4; nt++)
      #pragma unroll
      for (int i = 0; i < 4; i++)
        Qws[(size_t)(b0 + mt*16 + hi*4 + i)*512 + cb + nt*16 + j] = f2bf(qa[mt][nt][i]);
}

// ---------------- Q kernel (qk path): 1024 thr, 32 batches, normalized-input staging ----------------
__global__ __launch_bounds__(1024) void ca_q_kernel_qk(const float* __restrict__ state,
    const int* __restrict__ agp, const float* __restrict__ stats,
    const float* __restrict__ bs, const unsigned short* __restrict__ WsF,
    const unsigned short* __restrict__ WqF, const unsigned short* __restrict__ WkF2,
    unsigned short* __restrict__ QKws){
  __shared__ unsigned short U[2][16*512];   // 32KB: per-group union Alds/SE/Qlds
  __shared__ float bias_s[512];
  int tid = threadIdx.x, lane = tid & 63, w = tid >> 6;
  int g16 = w >> 3, wl = w & 7;
  int j = lane & 15, hi = lane >> 4;
  int b0 = blockIdx.x * 32 + g16 * 16;
  int ag = agp[0];
  f32x4 zero4 = {0.f, 0.f, 0.f, 0.f};
  unsigned short* Alds = U[g16];
  unsigned short* SE = U[g16];
  unsigned short* Qlds = U[g16];
  int sub = tid & 511;

  {
    int row = sub >> 5, kg = sub & 31;
    int kg0 = kg * 8;
    f32x4 rc0 = *(const f32x4*)(stats + kg0);
    f32x4 rc1 = *(const f32x4*)(stats + kg0 + 4);
    f32x4 mr0 = *(const f32x4*)(stats + 256 + kg0);
    f32x4 mr1 = *(const f32x4*)(stats + 256 + kg0 + 4);
    const float* p = state + (((size_t)(b0 + row) * 16 + ag) << 8) + kg0;
    f32x4 v0 = *(const f32x4*)p, v1 = *(const f32x4*)(p + 4);
    v0 = v0 * rc0 - mr0;
    v1 = v1 * rc1 - mr1;
    ushort8 hv;
    hv[0]=f2bf(v0[0]); hv[1]=f2bf(v0[1]); hv[2]=f2bf(v0[2]); hv[3]=f2bf(v0[3]);
    hv[4]=f2bf(v1[0]); hv[5]=f2bf(v1[1]); hv[6]=f2bf(v1[2]); hv[7]=f2bf(v1[3]);
    *(ushort8*)&Alds[row*256 + ((kg ^ (row & 7)) << 3)] = hv;
  }
  if (tid < 512) bias_s[tid] = bs[tid];
  __syncthreads();

  int cb = wl * 64;

  // GEMM1 (swapped): s_enc
  f32x4 acc[4];
  #pragma unroll
  for (int a2 = 0; a2 < 4; a2++) acc[a2] = zero4;
  #pragma unroll
  for (int kk = 0; kk < 8; kk++){
    short8 bfr[4];
    #pragma unroll
    for (int nt = 0; nt < 4; nt++)
      bfr[nt] = *(const short8*)&WsF[(size_t)((wl*8 + kk)*4 + nt)*512 + lane*8];
    short8 afr = *(const short8*)&Alds[j*256 + ((((kk << 2) | hi) ^ (j & 7)) << 3)];
    #pragma unroll
    for (int nt = 0; nt < 4; nt++)
      acc[nt] = __builtin_amdgcn_mfma_f32_16x16x32_bf16(bfr[nt], afr, acc[nt], 0, 0, 0);
  }
  __syncthreads();   // Alds dead; SE overlays it
  #pragma unroll
  for (int nt = 0; nt < 4; nt++){
    int nb = cb + nt*16 + hi*4;
    int g = nb >> 3;
    bfu4 pk;
    #pragma unroll
    for (int i = 0; i < 4; i++) pk[i] = f2bf(leaky(acc[nt][i] + bias_s[nb + i]));
    *(bfu4*)&SE[j*512 + ((g ^ (j & 7)) << 3) + (hi & 1)*4] = pk;
  }
  __syncthreads();

  // q-GEMM (swapped)
  f32x4 qa[4];
  #pragma unroll
  for (int a2 = 0; a2 < 4; a2++) qa[a2] = zero4;
  #pragma unroll
  for (int kk = 0; kk < 16; kk++){
    short8 bfr[4];
    #pragma unroll
    for (int nt = 0; nt < 4; nt++)
      bfr[nt] = *(const short8*)&WqF[(size_t)((wl*16 + kk)*4 + nt)*512 + lane*8];
    short8 afr = *(const short8*)&SE[j*512 + ((((kk << 2) | hi) ^ (j & 7)) << 3)];
    #pragma unroll
    for (int nt = 0; nt < 4; nt++)
      qa[nt] = __builtin_amdgcn_mfma_f32_16x16x32_bf16(bfr[nt], afr, qa[nt], 0, 0, 0);
  }
  __syncthreads();   // SE dead; Qlds overlays it
  #pragma unroll
  for (int nt = 0; nt < 4; nt++){
    int nb = cb + nt*16 + hi*4;
    int g = nb >> 3;
    bfu4 pk;
    #pragma unroll
    for (int i = 0; i < 4; i++) pk[i] = f2bf(qa[nt][i]);
    *(bfu4*)&Qlds[j*512 + ((g ^ (j & 7)) << 3) + (hi & 1)*4] = pk;
  }
  __syncthreads();

  // qk GEMM (swapped): C rows = n, cols = batch j; packed 8B stores
  short8 aq[2];
  #pragma unroll
  for (int kq = 0; kq < 2; kq++){
    int gq = wl*8 + kq*4 + hi;
    aq[kq] = *(const short8*)&Qlds[j*512 + ((gq ^ (j & 7)) << 3)];
  }
  for (int nt = 0; nt < 32; nt++){
    short8 bf0 = *(const short8*)&WkF2[(size_t)((wl*32 + nt)*2 + 0)*512 + lane*8];
    short8 bf1 = *(const short8*)&WkF2[(size_t)((wl*32 + nt)*2 + 1)*512 + lane*8];
    f32x4 qt = zero4;
    qt = __builtin_amdgcn_mfma_f32_16x16x32_bf16(bf0, aq[0], qt, 0, 0, 0);
    qt = __builtin_amdgcn_mfma_f32_16x16x32_bf16(bf1, aq[1], qt, 0, 0, 0);
    bfu4 pk;
    pk[0] = f2bf(qt[0]); pk[1] = f2bf(qt[1]); pk[2] = f2bf(qt[2]); pk[3] = f2bf(qt[3]);
    *(bfu4*)&QKws[((size_t)(b0 + j)*8 + wl)*512 + nt*16 + hi*4] = pk;
  }
}

// ---------------- main kernel (qk path): 4 batches/block (64 rows), 2 blocks/CU, 4 waves/SIMD ----------------
__global__ __launch_bounds__(512) void ca_main_kernel_qk(const float* __restrict__ state,
    const int* __restrict__ agp, const float* __restrict__ stats,
    const unsigned short* __restrict__ WcF, const float* __restrict__ bc,
    const unsigned short* __restrict__ WvF, const unsigned short* __restrict__ QKws,
    float* __restrict__ out){
  __shared__ unsigned short U[64*512];      // 64KB union: Alds (stride 256), SA (stride 512 swz)
  __shared__ float bias_s[512];
  __shared__ float Wl[4*16*8];              // wgt[b][a][h], 2KB
  unsigned short* Alds = U;
  unsigned short* SA = U;
  int tid = threadIdx.x, lane = tid & 63, w = tid >> 6;
  int j = lane & 15, hi = lane >> 4;
  int b0 = blockIdx.x * 4;
  int ag = agp[0];
  f32x4 zero4 = {0.f, 0.f, 0.f, 0.f};
  short8 zero8 = {0,0,0,0,0,0,0,0};

  {
    int kg0 = (tid & 31) * 8;
    f32x4 rc0 = *(const f32x4*)(stats + 512 + kg0);
    f32x4 rc1 = *(const f32x4*)(stats + 512 + kg0 + 4);
    f32x4 mr0 = *(const f32x4*)(stats + 768 + kg0);
    f32x4 mr1 = *(const f32x4*)(stats + 768 + kg0 + 4);
    f32x4 st0[4], st1[4];
    #pragma unroll
    for (int it = 0; it < 4; it++){
      int s = tid + 512*it;
      int row = s >> 5;
      int bl = row >> 4, ai = row & 15;
      if (ai < 15){
        int a = ai + (ai >= ag ? 1 : 0);
        const float* p = state + (((size_t)(b0 + bl) * 16 + a) << 8) + kg0;
        st0[it] = *(const f32x4*)p;
        st1[it] = *(const f32x4*)(p + 4);
      } else { st0[it] = zero4; st1[it] = zero4; }
    }
    #pragma unroll
    for (int it = 0; it < 4; it++){
      int s = tid + 512*it;
      int row = s >> 5, kg = s & 31;
      int ai = row & 15;
      ushort8 hv = {0,0,0,0,0,0,0,0};
      if (ai < 15){
        f32x4 v0 = st0[it] * rc0 - mr0;
        f32x4 v1 = st1[it] * rc1 - mr1;
        hv[0]=f2bf(v0[0]); hv[1]=f2bf(v0[1]); hv[2]=f2bf(v0[2]); hv[3]=f2bf(v0[3]);
        hv[4]=f2bf(v1[0]); hv[5]=f2bf(v1[1]); hv[6]=f2bf(v1[2]); hv[7]=f2bf(v1[3]);
      }
      *(ushort8*)&Alds[row*256 + ((kg ^ (row & 7)) << 3)] = hv;
    }
  }
  bias_s[tid] = bc[tid];
  __syncthreads();

  int cb = w * 64;

  // ---- GEMM1 (swapped): sa_enc rows [0,64)
  f32x4 acc[4][4];
  #pragma unroll
  for (int a1 = 0; a1 < 4; a1++)
    #pragma unroll
    for (int a2 = 0; a2 < 4; a2++) acc[a1][a2] = zero4;
  {
    short8 bcur[4], bnxt[4];
    #pragma unroll
    for (int nt = 0; nt < 4; nt++)
      bcur[nt] = *(const short8*)&WcF[(size_t)((w*8 + 0)*4 + nt)*512 + lane*8];
    #pragma unroll 2
    for (int kk = 0; kk < 8; kk++){
      if (kk < 7){
        #pragma unroll
        for (int nt = 0; nt < 4; nt++)
          bnxt[nt] = *(const short8*)&WcF[(size_t)((w*8 + kk + 1)*4 + nt)*512 + lane*8];
      }
      #pragma unroll
      for (int mt = 0; mt < 4; mt++){
        int row = mt*16 + j;
        short8 afr = *(const short8*)&Alds[row*256 + ((((kk << 2) | hi) ^ (row & 7)) << 3)];
        #pragma unroll
        for (int nt = 0; nt < 4; nt++)
          acc[mt][nt] = __builtin_amdgcn_mfma_f32_16x16x32_bf16(bcur[nt], afr, acc[mt][nt], 0, 0, 0);
      }
      #pragma unroll
      for (int nt = 0; nt < 4; nt++) bcur[nt] = bnxt[nt];
    }
  }
  __syncthreads();   // Alds dead; SA overlays
  #pragma unroll
  for (int mt = 0; mt < 4; mt++)
    #pragma unroll
    for (int nt = 0; nt < 4; nt++){
      int m = mt*16 + j;
      int nb = cb + nt*16 + hi*4;
      int g = nb >> 3;
      bfu4 pk;
      #pragma unroll
      for (int i = 0; i < 4; i++) pk[i] = f2bf(leaky(acc[mt][nt][i] + bias_s[nb + i]));
      *(bfu4*)&SA[m*512 + ((g ^ (m & 7)) << 3) + (hi & 1)*4] = pk;
    }
  __syncthreads();

  // ---- scores: waves 0..3 own batch b0+w (M=16 agents x 8 heads, K=512)
  if (w < 4){
    f32x4 qs = zero4;
    size_t qbase = ((size_t)(b0 + w)*8 + (j & 7))*512;
    #pragma unroll
    for (int kk = 0; kk < 16; kk++){
      short8 bq = *(const short8*)&QKws[qbase + kk*32 + hi*8];
      if (j >= 8) bq = zero8;
      int row = w*16 + j;
      short8 afr = *(const short8*)&SA[row*512 + ((((kk << 2) | hi) ^ (row & 7)) << 3)];
      qs = __builtin_amdgcn_mfma_f32_16x16x32_bf16(afr, bq, qs, 0, 0, 0);
    }
    float sv0 = qs[0], sv1 = qs[1], sv2 = qs[2], sv3 = qs[3];
    sv3 = (hi == 3) ? -1e30f : sv3;         // mask pad agent a=15
    float m = fmaxf(fmaxf(sv0, sv1), fmaxf(sv2, sv3));
    m = fmaxf(m, __shfl_xor(m, 16)); m = fmaxf(m, __shfl_xor(m, 32));
    float e0 = __expf(sv0-m), e1 = __expf(sv1-m), e2 = __expf(sv2-m), e3 = __expf(sv3-m);
    float sum = e0 + e1 + e2 + e3;
    sum += __shfl_xor(sum, 16); sum += __shfl_xor(sum, 32);
    float inv = 1.f / sum;
    if (j < 8){
      Wl[w*128 + (hi*4+0)*8 + j] = e0*inv;
      Wl[w*128 + (hi*4+1)*8 + j] = e1*inv;
      Wl[w*128 + (hi*4+2)*8 + j] = e2*inv;
      Wl[w*128 + (hi*4+3)*8 + j] = e3*inv;
    }
  }

  // ---- GEMM2-V (unswapped), rows [0,64)
  f32x4 va[4][4];
  #pragma unroll
  for (int a1 = 0; a1 < 4; a1++)
    #pragma unroll
    for (int a2 = 0; a2 < 4; a2++) va[a1][a2] = zero4;
  {
    short8 bcur[4], bnxt[4];
    #pragma unroll
    for (int nt = 0; nt < 4; nt++)
      bcur[nt] = *(const short8*)&WvF[(size_t)((w*16 + 0)*4 + nt)*512 + lane*8];
    #pragma unroll 2
    for (int kk = 0; kk < 16; kk++){
      if (kk < 15){
        #pragma unroll
        for (int nt = 0; nt < 4; nt++)
          bnxt[nt] = *(const short8*)&WvF[(size_t)((w*16 + kk + 1)*4 + nt)*512 + lane*8];
      }
      #pragma unroll
      for (int mt = 0; mt < 4; mt++){
        int row = mt*16 + j;
        short8 afr = *(const short8*)&SA[row*512 + ((((kk << 2) | hi) ^ (row & 7)) << 3)];
        #pragma unroll
        for (int nt = 0; nt < 4; nt++)
          va[mt][nt] = __builtin_amdgcn_mfma_f32_16x16x32_bf16(afr, bcur[nt], va[mt][nt], 0, 0, 0);
      }
      #pragma unroll
      for (int nt = 0; nt < 4; nt++) bcur[nt] = bnxt[nt];
    }
  }
  __syncthreads();   // Wl writes (pre-V) now visible to all waves

  // ---- att = sum_a wgt * leaky(V); wave w = head w reads wgt[mt][a][w]
  #pragma unroll
  for (int mt = 0; mt < 4; mt++){
    float w0 = Wl[mt*128 + (hi*4+0)*8 + w];
    float w1 = Wl[mt*128 + (hi*4+1)*8 + w];
    float w2 = Wl[mt*128 + (hi*4+2)*8 + w];
    float w3 = Wl[mt*128 + (hi*4+3)*8 + w];
    float ap0 = w0*leaky(va[mt][0][0]) + w1*leaky(va[mt][0][1]) + w2*leaky(va[mt][0][2]) + w3*leaky(va[mt][0][3]);
    float ap1 = w0*leaky(va[mt][1][0]) + w1*leaky(va[mt][1][1]) + w2*leaky(va[mt][1][2]) + w3*leaky(va[mt][1][3]);
    float ap2 = w0*leaky(va[mt][2][0]) + w1*leaky(va[mt][2][1]) + w2*leaky(va[mt][2][2]) + w3*leaky(va[mt][2][3]);
    float ap3 = w0*leaky(va[mt][3][0]) + w1*leaky(va[mt][3][1]) + w2*leaky(va[mt][3][2]) + w3*leaky(va[mt][3][3]);
    ap0 += __shfl_xor(ap0, 16); ap0 += __shfl_xor(ap0, 32);
    ap1 += __shfl_xor(ap1, 16); ap1 += __shfl_xor(ap1, 32);
    ap2 += __shfl_xor(ap2, 16); ap2 += __shfl_xor(ap2, 32);
    ap3 += __shfl_xor(ap3, 16); ap3 += __shfl_xor(ap3, 32);
    float val = (hi == 0) ? ap0 : (hi == 1) ? ap1 : (hi == 2) ? ap2 : ap3;
    out[(size_t)(b0 + mt)*512 + cb + lane] = val;
  }
}

// ---------------- main kernel (fallback = R9, unchanged) ----------------
__global__ __launch_bounds__(512) void ca_main_kernel(const float* __restrict__ state,
    const int* __restrict__ agp,
    const unsigned short* __restrict__ WcT, const float* __restrict__ bcp,
    const unsigned short* __restrict__ WkT, const unsigned short* __restrict__ WvT,
    const unsigned short* __restrict__ Qws, float* __restrict__ out){
  __shared__ unsigned short U[128*512];
  __shared__ unsigned short Qs[8*512];
  __shared__ float bias_s[512];
  unsigned short* Alds = U;
  unsigned short* SA = U;
  int tid = threadIdx.x, lane = tid & 63, w = tid >> 6;
  int j = lane & 15, hi = lane >> 4;
  int b0 = blockIdx.x * 8;
  int ag = agp[0];
  f32x4 zero4 = {0.f, 0.f, 0.f, 0.f};

  #pragma unroll
  for (int g = 0; g < 2; g++){
    f32x4 st0[4], st1[4];
    #pragma unroll
    for (int it = 0; it < 4; it++){
      int s = tid + 512*(g*4 + it);
      int row = s >> 5, kg = s & 31;
      int bl = row >> 4, ai = row & 15;
      if (ai < 15){
        int a = ai + (ai >= ag ? 1 : 0);
        const float* p = state + (((size_t)(b0 + bl) * 16 + a) << 8) + kg * 8;
        st0[it] = *(const f32x4*)p;
        st1[it] = *(const f32x4*)(p + 4);
      } else { st0[it] = zero4; st1[it] = zero4; }
    }
    #pragma unroll
    for (int it = 0; it < 4; it++){
      int s = tid + 512*(g*4 + it);
      int row = s >> 5, kg = s & 31;
      ushort8 hv;
      hv[0]=f2bf(st0[it][0]); hv[1]=f2bf(st0[it][1]); hv[2]=f2bf(st0[it][2]); hv[3]=f2bf(st0[it][3]);
      hv[4]=f2bf(st1[it][0]); hv[5]=f2bf(st1[it][1]); hv[6]=f2bf(st1[it][2]); hv[7]=f2bf(st1[it][3]);
      *(ushort8*)&Alds[row*256 + ((kg ^ (row & 7)) << 3)] = hv;
    }
  }
  *(ushort8*)&Qs[tid*8] = *(const ushort8*)&Qws[(size_t)b0*512 + tid*8];
  bias_s[tid] = bcp[tid];
  __syncthreads();

  int cb = w * 64;

  f32x4 acc[8][4];
  #pragma unroll
  for (int a1 = 0; a1 < 8; a1++)
    #pragma unroll
    for (int a2 = 0; a2 < 4; a2++) acc[a1][a2] = zero4;
  {
    short8 bcur[4], bnxt[4];
    #pragma unroll
    for (int nt = 0; nt < 4; nt++)
      bcur[nt] = *(const short8*)&WcT[(size_t)(cb + nt*16 + j)*256 + hi*8];
    #pragma unroll 1
    for (int kk = 0; kk < 8; kk++){
      if (kk < 7){
        #pragma unroll
        for (int nt = 0; nt < 4; nt++)
          bnxt[nt] = *(const short8*)&WcT[(size_t)(cb + nt*16 + j)*256 + (kk+1)*32 + hi*8];
      }
      #pragma unroll
      for (int mt = 0; mt < 8; mt++){
        int row = mt*16 + j;
        short8 afr = *(const short8*)&Alds[row*256 + ((((kk << 2) | hi) ^ (row & 7)) << 3)];
        #pragma unroll
        for (int nt = 0; nt < 4; nt++)
          acc[mt][nt] = __builtin_amdgcn_mfma_f32_16x16x32_bf16(afr, bcur[nt], acc[mt][nt], 0, 0, 0);
      }
      #pragma unroll
      for (int nt = 0; nt < 4; nt++) bcur[nt] = bnxt[nt];
    }
  }
  __syncthreads();
  #pragma unroll
  for (int mt = 0; mt < 8; mt++)
    #pragma unroll
    for (int nt = 0; nt < 4; nt++)
      #pragma unroll
      for (int i = 0; i < 4; i++){
        int row = mt*16 + hi*4 + i, col = cb + nt*16 + j;
        float x = leaky(acc[mt][nt][i] + bias_s[col]);
        SA[row*512 + ((((col >> 3) ^ (row & 7)) << 3) | (col & 7))] = f2bf(x);
      }
  __syncthreads();

  f32x4 ka[8][4];
  #pragma unroll
  for (int a1 = 0; a1 < 8; a1++)
    #pragma unroll
    for (int a2 = 0; a2 < 4; a2++) ka[a1][a2] = zero4;
  {
    short8 bcur[4], bnxt[4];
    #pragma unroll
    for (int nt = 0; nt < 4; nt++)
      bcur[nt] = *(const short8*)&WkT[(size_t)(cb + nt*16 + j)*512 + hi*8];
    #pragma unroll 1
    for (int kk = 0; kk < 16; kk++){
      if (kk < 15){
        #pragma unroll
        for (int nt = 0; nt < 4; nt++)
          bnxt[nt] = *(const short8*)&WkT[(size_t)(cb + nt*16 + j)*512 + (kk+1)*32 + hi*8];
      }
      #pragma unroll
      for (int mt = 0; mt < 8; mt++){
        int row = mt*16 + j;
        short8 afr = *(const short8*)&SA[row*512 + ((((kk << 2) | hi) ^ (row & 7)) << 3)];
        #pragma unroll
        for (int nt = 0; nt < 4; nt++)
          ka[mt][nt] = __builtin_amdgcn_mfma_f32_16x16x32_bf16(afr, bcur[nt], ka[mt][nt], 0, 0, 0);
      }
      #pragma unroll
      for (int nt = 0; nt < 4; nt++) bcur[nt] = bnxt[nt];
    }
  }

  float wgt[8][4];
  #pragma unroll
  for (int mt = 0; mt < 8; mt++){
    float sv[4];
    #pragma unroll
    for (int i = 0; i < 4; i++){
      float t = 0.f;
      #pragma unroll
      for (int nt = 0; nt < 4; nt++)
        t += bf2f(Qs[mt*512 + cb + nt*16 + j]) * ka[mt][nt][i];
      t += __shfl_xor(t, 1); t += __shfl_xor(t, 2);
      t += __shfl_xor(t, 4); t += __shfl_xor(t, 8);
      sv[i] = t;
    }
    sv[3] = (hi == 3) ? -1e30f : sv[3];
    float m = fmaxf(fmaxf(sv[0], sv[1]), fmaxf(sv[2], sv[3]));
    m = fmaxf(m, __shfl_xor(m, 16)); m = fmaxf(m, __shfl_xor(m, 32));
    float e0 = __expf(sv[0]-m), e1 = __expf(sv[1]-m), e2 = __expf(sv[2]-m), e3 = __expf(sv[3]-m);
    float sum = e0 + e1 + e2 + e3;
    sum += __shfl_xor(sum, 16); sum += __shfl_xor(sum, 32);
    float inv = 1.f / sum;
    wgt[mt][0] = e0*inv; wgt[mt][1] = e1*inv; wgt[mt][2] = e2*inv; wgt[mt][3] = e3*inv;
  }

  f32x4 va[8][4];
  #pragma unroll
  for (int a1 = 0; a1 < 8; a1++)
    #pragma unroll
    for (int a2 = 0; a2 < 4; a2++) va[a1][a2] = zero4;
  {
    short8 bcur[4], bnxt[4];
    #pragma unroll
    for (int nt = 0; nt < 4; nt++)
      bcur[nt] = *(const short8*)&WvT[(size_t)(cb + nt*16 + j)*512 + hi*8];
    #pragma unroll 1
    for (int kk = 0; kk < 16; kk++){
      if (kk < 15){
        #pragma unroll
        for (int nt = 0; nt < 4; nt++)
          bnxt[nt] = *(const short8*)&WvT[(size_t)(cb + nt*16 + j)*512 + (kk+1)*32 + hi*8];
      }
      #pragma unroll
      for (int mt = 0; mt < 8; mt++){
        int row = mt*16 + j;
        short8 afr = *(const short8*)&SA[row*512 + ((((kk << 2) | hi) ^ (row & 7)) << 3)];
        #pragma unroll
        for (int nt = 0; nt < 4; nt++)
          va[mt][nt] = __builtin_amdgcn_mfma_f32_16x16x32_bf16(afr, bcur[nt], va[mt][nt], 0, 0, 0);
      }
      #pragma unroll
      for (int nt = 0; nt < 4; nt++) bcur[nt] = bnxt[nt];
    }
  }

  #pragma unroll
  for (int mt = 0; mt < 8; mt++){
    float ap0 = 0.f, ap1 = 0.f, ap2 = 0.f, ap3 = 0.f;
    #pragma unroll
    for (int i = 0; i < 4; i++){
      float wv = wgt[mt][i];
      ap0 += wv * leaky(va[mt][0][i]);
      ap1 += wv * leaky(va[mt][1][i]);
      ap2 += wv * leaky(va[mt][2][i]);
      ap3 += wv * leaky(va[mt][3][i]);
    }
    ap0 += __shfl_xor(ap0, 16); ap0 += __shfl_xor(ap0, 32);
    ap1 += __shfl_xor(ap1, 16); ap1 += __shfl_xor(ap1, 32);
    ap2 += __shfl_xor(ap2, 16); ap2 += __shfl_xor(ap2, 32);
    ap3 += __shfl_xor(ap3, 16); ap3 += __shfl_xor(ap3, 32);
    float val = (hi == 0) ? ap0 : (hi == 1) ? ap1 : (hi == 2) ? ap2 : ap3;
    out[(size_t)(b0 + mt)*512 + cb + lane] = val;
  }
}

extern "C" void kernel_launch(void* const* d_in, const int* in_sizes, int n_in,
                              void* d_out, int out_size, void* d_ws, size_t ws_size,
                              hipStream_t stream) {
  const float* state = (const float*)d_in[0];
  const int*   agp   = (const int*)d_in[1];
  const float* Ws    = (const float*)d_in[2];
  const float* bs    = (const float*)d_in[3];
  const float* Wc    = (const float*)d_in[4];
  const float* bc    = (const float*)d_in[5];
  const float* Wk    = (const float*)d_in[6];
  const float* Wq    = (const float*)d_in[7];
  const float* Wv    = (const float*)d_in[8];
  float* out = (float*)d_out;
  int B = in_sizes[0] / 4096;   // state is (B,16,256)

  char* wsb = (char*)d_ws;
  float* part  = (float*)wsb;                                   // 1 MB
  float* stats = (float*)(wsb + (1 << 20));                     // 4 KB
  float* bsp   = (float*)(wsb + (1 << 20) + 4096);              // 2 KB
  float* bcp   = (float*)(wsb + (1 << 20) + 6144);              // 2 KB
  unsigned short* WsT  = (unsigned short*)(wsb + (1 << 20) + 8192);
  unsigned short* WcT  = WsT  + 512*256;
  unsigned short* WkT  = WcT  + 512*256;
  unsigned short* WvT  = WkT  + 512*512;
  unsigned short* WqT  = WvT  + 512*512;
  unsigned short* WkF2 = WqT  + 512*512;         // fragment-major Wk (qk GEMM)
  unsigned short* Qws  = WkF2 + 512*512;         // B*512  (fallback only)
  unsigned short* QKws = Qws  + (size_t)B*512;   // B*8*512
  unsigned short* WsF  = Qws;                    // F-layouts overlay Qws (qk path)
  unsigned short* WcF  = WsF + 512*256;
  unsigned short* WqF  = WcF + 512*256;
  unsigned short* WvF  = WqF + 512*512;

  size_t need = ((size_t)(1 << 20) + 8192)
              + 2ull*(512*256 + 512*256 + 512*512 + 512*512 + 512*512 + 512*512)
              + 2ull*B*512 + 2ull*B*8*512;
  bool qkp = (ws_size >= need);

  hipLaunchKernelGGL(ca_stats_prep, dim3(1280), dim3(1024), 0, stream, state, agp, part, B,
                     Wk, Wv, Wq, Ws, Wc, WkF2, WvF, WqF, WsF, WcF);
  hipLaunchKernelGGL(ca_stats_final, dim3(8), dim3(1024), 0, stream, part, stats, 256, B);
  if (qkp){
    hipLaunchKernelGGL(ca_q_kernel_qk,   dim3(B/32),dim3(1024), 0, stream, state, agp, stats, bs, WsF, WqF, WkF2, QKws);
    hipLaunchKernelGGL(ca_main_kernel_qk,dim3(B/4), dim3(512), 0, stream, state, agp, stats, WcF, bc, WvF, QKws, out);
  } else {
    hipLaunchKernelGGL(ca_prep_sc,       dim3(512), dim3(256), 0, stream, Ws, bs, Wc, bc, stats, WsT, WcT, bsp, bcp);
    hipLaunchKernelGGL(ca_prep_kvq,      dim3(1536),dim3(512), 0, stream, Wk, Wv, Wq, WkT, WvT, WqT);
    hipLaunchKernelGGL(ca_q_kernel,      dim3(B/32),dim3(512), 0, stream, state, agp, WsT, bsp, WqT, Qws);
    hipLaunchKernelGGL(ca_main_kernel,   dim3(B/8), dim3(512), 0, stream, state, agp, WcT, bcp, WkT, WvT, Qws, out);
  }
}